// Round 1
// baseline (10182.514 us; speedup 1.0000x reference)
//
#include <hip/hip_runtime.h>
#include <math.h>

#define LEAKY(v, s) ((v) >= 0.f ? (v) : (s) * (v))

__device__ __forceinline__ float sig_(float x) { return 1.f / (1.f + expf(-x)); }

// ---------------- utility kernels ----------------
__global__ void transpose_f32(const float* __restrict__ in, float* __restrict__ out,
                              int R, int C) {
  int idx = blockIdx.x * blockDim.x + threadIdx.x;
  if (idx < R * C) {
    int c = idx % C, r = idx / C;
    out[c * R + r] = in[idx];
  }
}

__global__ void add_pair_f32(const float* __restrict__ a, const float* __restrict__ b,
                             float* __restrict__ out, int n) {
  int i = blockIdx.x * blockDim.x + threadIdx.x;
  if (i < n) out[i] = a[i] + b[i];
}

__global__ void zero_f32(float* p, int n) {
  int i = blockIdx.x * blockDim.x + threadIdx.x;
  if (i < n) p[i] = 0.f;
}

// ---------------- direct conv + leaky ----------------
template <int K, int S, bool PAD>
__global__ void conv_leaky(const float* __restrict__ x, const float* __restrict__ w,
                           const float* __restrict__ bias, float* __restrict__ out,
                           int N, int Cin, int Hin, int Win,
                           int Cout, int Hout, int Wout, int pad, float slope) {
  int total = N * Cout * Hout * Wout;
  int idx = blockIdx.x * blockDim.x + threadIdx.x;
  if (idx >= total) return;
  int ow = idx % Wout;
  int t = idx / Wout;
  int oh = t % Hout; t /= Hout;
  int co = t % Cout;
  int n = t / Cout;
  float acc = bias[co];
  const float* wb = w + co * Cin * K * K;
  int ih0 = oh * S - pad, iw0 = ow * S - pad;
  for (int ci = 0; ci < Cin; ++ci) {
    const float* xp = x + (n * Cin + ci) * Hin * Win;
    const float* wp = wb + ci * K * K;
#pragma unroll
    for (int kh = 0; kh < K; ++kh) {
      int ih = ih0 + kh;
      if (PAD) {
        if ((unsigned)ih >= (unsigned)Hin) continue;
      }
      const float* xr = xp + ih * Win;
#pragma unroll
      for (int kw = 0; kw < K; ++kw) {
        int iw = iw0 + kw;
        if (PAD) {
          if ((unsigned)iw >= (unsigned)Win) continue;
        }
        acc = fmaf(xr[iw], wp[kh * K + kw], acc);
      }
    }
  }
  out[idx] = LEAKY(acc, slope);
}

// ---------------- FC (in [B,K] @ wT [K,N] + bias, act) ----------------
// act: 0 none, 1 leaky(slope), 2 sigmoid. BB rows of B per thread.
template <int BB>
__global__ void fc_act(const float* __restrict__ in, const float* __restrict__ wT,
                       const float* __restrict__ bias, float* __restrict__ out,
                       int Brows, int K, int N, int act, float slope) {
  int idx = blockIdx.x * blockDim.x + threadIdx.x;
  int nb = Brows / BB;
  if (idx >= nb * N) return;
  int j = idx % N;
  int b0 = (idx / N) * BB;
  float acc[BB];
  float bj = bias[j];
#pragma unroll
  for (int i = 0; i < BB; ++i) acc[i] = bj;
  const float* ip = in + b0 * K;
  for (int k = 0; k < K; ++k) {
    float wv = wT[k * N + j];
#pragma unroll
    for (int i = 0; i < BB; ++i) acc[i] = fmaf(ip[i * K + k], wv, acc[i]);
  }
#pragma unroll
  for (int i = 0; i < BB; ++i) {
    float v = acc[i];
    if (act == 1) v = LEAKY(v, slope);
    else if (act == 2) v = sig_(v);
    out[(b0 + i) * N + j] = v;
  }
}

// ---------------- fused LSTM layer step ----------------
// pre[b][g*512+u] = (base ? base[b][g*512+u] : bias[g*512+u])
//                 + sum_k inA[b][k] * wAT[k][g*512+u]
//                 + (inB ? sum_k inB[b][k] * wBT[k][g*512+u] : 0)
// then PyTorch-order gates (i,f,g,o), c/h update, optional ys store.
// Block: 256 threads = 64 u-lanes x 4 k-slices. Grid: 8 u-groups x (128/BB) b-groups.
template <int BB>
__global__ __launch_bounds__(256) void lstm_step(
    const float* __restrict__ base, const float* __restrict__ bias,
    const float* __restrict__ inA, const float* __restrict__ wAT,
    const float* __restrict__ inB, const float* __restrict__ wBT,
    const float* c_in, float* c_out,
    float* __restrict__ h_out, float* __restrict__ ys_out) {
  constexpr int H = 512, G4 = 2048, KS = 4, KCH = H / KS;  // KCH=128
  int tid = threadIdx.x;
  int ul = tid & 63;
  int ks = tid >> 6;
  int u = (blockIdx.x & 7) * 64 + ul;
  int b0 = (blockIdx.x >> 3) * BB;

  float acc[4][BB];
#pragma unroll
  for (int g = 0; g < 4; ++g)
#pragma unroll
    for (int i = 0; i < BB; ++i) acc[g][i] = 0.f;

  int k0 = ks * KCH;
  {
    const float* wp = wAT + k0 * G4 + u;
    const float* ip = inA + b0 * H + k0;
    for (int k = 0; k < KCH; ++k) {
      float w0 = wp[0 * H], w1 = wp[1 * H], w2 = wp[2 * H], w3 = wp[3 * H];
      wp += G4;
#pragma unroll
      for (int i = 0; i < BB; ++i) {
        float hv = ip[i * H + k];
        acc[0][i] = fmaf(hv, w0, acc[0][i]);
        acc[1][i] = fmaf(hv, w1, acc[1][i]);
        acc[2][i] = fmaf(hv, w2, acc[2][i]);
        acc[3][i] = fmaf(hv, w3, acc[3][i]);
      }
    }
  }
  if (inB) {
    const float* wp = wBT + k0 * G4 + u;
    const float* ip = inB + b0 * H + k0;
    for (int k = 0; k < KCH; ++k) {
      float w0 = wp[0 * H], w1 = wp[1 * H], w2 = wp[2 * H], w3 = wp[3 * H];
      wp += G4;
#pragma unroll
      for (int i = 0; i < BB; ++i) {
        float hv = ip[i * H + k];
        acc[0][i] = fmaf(hv, w0, acc[0][i]);
        acc[1][i] = fmaf(hv, w1, acc[1][i]);
        acc[2][i] = fmaf(hv, w2, acc[2][i]);
        acc[3][i] = fmaf(hv, w3, acc[3][i]);
      }
    }
  }

  __shared__ float red[KS][4][BB][64];
#pragma unroll
  for (int g = 0; g < 4; ++g)
#pragma unroll
    for (int i = 0; i < BB; ++i) red[ks][g][i][ul] = acc[g][i];
  __syncthreads();

  if (ks == 0) {
#pragma unroll
    for (int i = 0; i < BB; ++i) {
      int b = b0 + i;
      float p[4];
#pragma unroll
      for (int g = 0; g < 4; ++g) {
        float s = red[0][g][i][ul] + red[1][g][i][ul] + red[2][g][i][ul] + red[3][g][i][ul];
        s += base ? base[b * G4 + g * H + u] : bias[g * H + u];
        p[g] = s;
      }
      float cprev = c_in[b * H + u];
      float ig = sig_(p[0]);
      float fg = sig_(p[1]);
      float gg = tanhf(p[2]);
      float og = sig_(p[3]);
      float cn = fg * cprev + ig * gg;
      float hn = og * tanhf(cn);
      c_out[b * H + u] = cn;
      h_out[b * H + u] = hn;
      if (ys_out) ys_out[b * H + u] = hn;
    }
  }
}

// ---------------- launch ----------------
extern "C" void kernel_launch(void* const* d_in, const int* in_sizes, int n_in,
                              void* d_out, int out_size, void* d_ws, size_t ws_size,
                              hipStream_t stream) {
  const float* x   = (const float*)d_in[0];
  const float* w1  = (const float*)d_in[1];  const float* b1 = (const float*)d_in[2];
  const float* w2  = (const float*)d_in[3];  const float* b2 = (const float*)d_in[4];
  const float* w3  = (const float*)d_in[5];  const float* b3 = (const float*)d_in[6];
  const float* w4  = (const float*)d_in[7];  const float* b4 = (const float*)d_in[8];
  const float* w5  = (const float*)d_in[9];  const float* b5 = (const float*)d_in[10];
  const float* wih0 = (const float*)d_in[11]; const float* whh0 = (const float*)d_in[12];
  const float* bih0 = (const float*)d_in[13]; const float* bhh0 = (const float*)d_in[14];
  const float* wih1 = (const float*)d_in[15]; const float* whh1 = (const float*)d_in[16];
  const float* bih1 = (const float*)d_in[17]; const float* bhh1 = (const float*)d_in[18];
  const float* fw1 = (const float*)d_in[19]; const float* fb1 = (const float*)d_in[20];
  const float* fw2 = (const float*)d_in[21]; const float* fb2 = (const float*)d_in[22];
  float* out = (float*)d_out;

  // workspace layout (elements, f32). R1/R2 are reused ping-pong activation regions.
  float* ws    = (float*)d_ws;
  float* R1    = ws;                    // 8388608  (conv1 out / conv3 out / feat)
  float* R2    = R1 + 8388608;          // 2768896  (conv2 out / conv4 out)
  float* wih0T = R2 + 2768896;          // 1048576
  float* whh0T = wih0T + 1048576;       // 1048576
  float* wih1T = whh0T + 1048576;       // 1048576
  float* whh1T = wih1T + 1048576;       // 1048576
  float* fw1T  = whh1T + 1048576;       // 262144
  float* fw2T  = fw1T + 262144;         // 6656
  float* bg0   = fw2T + 6656;           // 2048
  float* bg1   = bg0 + 2048;            // 2048
  float* xw0   = bg1 + 2048;            // 262144
  float* h0a   = xw0 + 262144;          // 65536
  float* h0b   = h0a + 65536;           // 65536
  float* h1a   = h0b + 65536;           // 65536
  float* h1b   = h1a + 65536;           // 65536
  float* c0    = h1b + 65536;           // 65536
  float* c1    = c0 + 65536;            // 65536
  float* ys    = c1 + 65536;            // 1310720
  float* fc1o  = ys + 1310720;          // 1310720
  // total ~18.9M floats = ~75.6 MB

  float* A1 = R1;   // [128,64,32,32]
  float* A2 = R2;   // [128,128,13,13]
  float* A3 = R1;   // [128,256,9,9]   (A1 dead)
  float* A4 = R2;   // [128,512,5,5]   (A2 dead)
  float* feat = R1; // [128,512]       (A3 dead)

  dim3 blk(256);

  // weight transposes + combined biases (per-call; cheap)
  transpose_f32<<<4096, blk, 0, stream>>>(wih0, wih0T, 2048, 512);
  transpose_f32<<<4096, blk, 0, stream>>>(whh0, whh0T, 2048, 512);
  transpose_f32<<<4096, blk, 0, stream>>>(wih1, wih1T, 2048, 512);
  transpose_f32<<<4096, blk, 0, stream>>>(whh1, whh1T, 2048, 512);
  transpose_f32<<<1024, blk, 0, stream>>>(fw1, fw1T, 512, 512);
  transpose_f32<<<26, blk, 0, stream>>>(fw2, fw2T, 13, 512);
  add_pair_f32<<<8, blk, 0, stream>>>(bih0, bhh0, bg0, 2048);
  add_pair_f32<<<8, blk, 0, stream>>>(bih1, bhh1, bg1, 2048);
  zero_f32<<<1536, blk, 0, stream>>>(h0a, 393216);  // h0a,h0b,h1a,h1b,c0,c1 contiguous

  // conv stack (f32 direct, leaky 0.2)
  conv_leaky<7, 2, true><<<32768, blk, 0, stream>>>(x, w1, b1, A1, 128, 3, 64, 64, 64, 32, 32, 3, 0.2f);
  conv_leaky<7, 2, false><<<10816, blk, 0, stream>>>(A1, w2, b2, A2, 128, 64, 32, 32, 128, 13, 13, 0, 0.2f);
  conv_leaky<5, 1, false><<<10368, blk, 0, stream>>>(A2, w3, b3, A3, 128, 128, 13, 13, 256, 9, 9, 0, 0.2f);
  conv_leaky<5, 1, false><<<6400, blk, 0, stream>>>(A3, w4, b4, A4, 128, 256, 9, 9, 512, 5, 5, 0, 0.2f);
  conv_leaky<5, 1, false><<<256, blk, 0, stream>>>(A4, w5, b5, feat, 128, 512, 5, 5, 512, 1, 1, 0, 0.2f);

  // xW0 = feat @ wih0.T + (bih0+bhh0)   [128,2048]
  fc_act<8><<<128, blk, 0, stream>>>(feat, wih0T, bg0, xw0, 128, 512, 2048, 0, 0.f);

  // 2-layer LSTM, 20 steps
  float* h0buf[2] = {h0a, h0b};
  float* h1buf[2] = {h1a, h1b};
  for (int t = 0; t < 20; ++t) {
    int p = t & 1;
    lstm_step<4><<<256, blk, 0, stream>>>(xw0, nullptr, h0buf[p], whh0T, nullptr, nullptr,
                                          c0, c0, h0buf[p ^ 1], nullptr);
    lstm_step<4><<<256, blk, 0, stream>>>(nullptr, bg1, h0buf[p ^ 1], wih1T, h1buf[p], whh1T,
                                          c1, c1, h1buf[p ^ 1], ys + t * 65536);
  }

  // FC head: leaky(ys @ fw1.T + fb1, 0.01) -> sigmoid(@ fw2.T + fb2)
  fc_act<8><<<640, blk, 0, stream>>>(ys, fw1T, fb1, fc1o, 2560, 512, 512, 1, 0.01f);
  fc_act<1><<<130, blk, 0, stream>>>(fc1o, fw2T, fb2, out, 2560, 512, 13, 2, 0.f);
}

// Round 3
// 1765.733 us; speedup vs baseline: 5.7667x; 5.7667x over previous
//
#include <hip/hip_runtime.h>
#include <math.h>

typedef unsigned short ushort_t;
typedef _Float16 half_t;
typedef __attribute__((ext_vector_type(8))) _Float16 f16x8;
typedef __attribute__((ext_vector_type(4))) _Float16 f16x4;
typedef __attribute__((ext_vector_type(4))) float f32x4;

#define LEAKY(v, s) ((v) >= 0.f ? (v) : (s) * (v))

__device__ __forceinline__ float sig_(float x) { return 1.f / (1.f + expf(-x)); }
__device__ __forceinline__ half_t f2h(float f) { return (half_t)f; }  // RNE v_cvt_f16_f32

#define GLD(gp, lp)                                              \
  __builtin_amdgcn_global_load_lds(                              \
      (const __attribute__((address_space(1))) void*)(gp),       \
      (__attribute__((address_space(3))) void*)(lp), 16, 0, 0)

// ---------------- utility kernels ----------------
__global__ void transpose_f32(const float* __restrict__ in, float* __restrict__ out,
                              int R, int C) {
  int idx = blockIdx.x * blockDim.x + threadIdx.x;
  if (idx < R * C) {
    int c = idx % C, r = idx / C;
    out[c * R + r] = in[idx];
  }
}

__global__ void add_pair_f32(const float* __restrict__ a, const float* __restrict__ b,
                             float* __restrict__ out, int n) {
  int i = blockIdx.x * blockDim.x + threadIdx.x;
  if (i < n) out[i] = a[i] + b[i];
}

__global__ void zero_f32(float* p, int n) {
  int i = blockIdx.x * blockDim.x + threadIdx.x;
  if (i < n) p[i] = 0.f;
}

// x [128,3,64,64] f32 -> xpad [128,70,70,8] fp16, spatial pad 3, channel pad to 8
__global__ void pad_x_kernel(const float* __restrict__ x, half_t* __restrict__ xp) {
  int i = blockIdx.x * blockDim.x + threadIdx.x;
  if (i >= 128 * 70 * 70 * 8) return;
  int c = i & 7;
  int t = i >> 3;
  int iw = t % 70; t /= 70;
  int ih = t % 70;
  int n = t / 70;
  float v = 0.f;
  if (c < 3 && ih >= 3 && ih < 67 && iw >= 3 && iw < 67)
    v = x[((n * 3 + c) * 64 + (ih - 3)) * 64 + (iw - 3)];
  xp[i] = f2h(v);
}

// w1 [64,3,7,7] -> [64][416] fp16; kg=(tap<<3)+ci, taps 0..48 valid ci 0..2, rest 0
__global__ void reorder_w1_kernel(const float* __restrict__ w, half_t* __restrict__ wr) {
  int i = blockIdx.x * blockDim.x + threadIdx.x;
  if (i >= 64 * 416) return;
  int kg = i % 416;
  int co = i / 416;
  int ci = kg & 7;
  int tap = kg >> 3;
  float v = 0.f;
  if (tap < 49 && ci < 3) {
    int kh = tap / 7, kw = tap % 7;
    v = w[((co * 3 + ci) * 7 + kh) * 7 + kw];
  }
  wr[i] = f2h(v);
}

// w [Cout,Cin,KH,KW] f32 -> wr [Cout][(kh*KW+kw)*Cin+ci] fp16
__global__ void reorder_w_kernel(const float* __restrict__ w, half_t* __restrict__ wr,
                                 int total, int K, int KW, int KH, int log2Cin) {
  int i = blockIdx.x * blockDim.x + threadIdx.x;
  if (i >= total) return;
  int kg = i % K;
  int co = i / K;
  int Cin = 1 << log2Cin;
  int ci = kg & (Cin - 1);
  int tap = kg >> log2Cin;
  int kh = tap / KW, kw = tap - kh * KW;
  wr[i] = f2h(w[(((size_t)co * Cin + ci) * KH + kh) * KW + kw]);
}

// ---------------- implicit-im2col fp16 MFMA conv ----------------
// C[co][px] = sum_k W[co][k] * X[k][px], k=(kh*KW+kw)*CIN+ci, px=(n,oh,ow)
// Tile 64(M=co) x 64(N=px) x 32(K). 4 waves, each 32x32 via 2x2 16x16x32 MFMA.
// Staging: global_load_lds 16B/lane, pre-swizzled source (chunk ^= row&3) so
// linear LDS + swizzled ds_read_b128 are conflict-free.
template <int KW, int S, int LOG2CIN, bool OUTF32>
__global__ __launch_bounds__(256) void conv_mfma(
    const half_t* __restrict__ xin, const half_t* __restrict__ wr,
    const float* __restrict__ bias, void* __restrict__ outp,
    int Hin, int Win, int Hout, int Wout, int Cout, int K, float slope) {
  constexpr int CIN = 1 << LOG2CIN;
  __shared__ half_t lds[4096];  // A: [0,2048) = [64 rows][32 k], B: [2048,4096)
  const int tid = threadIdx.x;
  const int lane = tid & 63, wid = tid >> 6;
  // staging role: row (co or px) = tid>>2, chunk = tid&3, swizzled source chunk
  const int sRow = tid >> 2, sCh = tid & 3;
  const int sSwz = sCh ^ (sRow & 3);
  const half_t* gA = wr + (size_t)(blockIdx.y * 64 + sRow) * K + sSwz * 8;
  // B pixel decompose (invariant over K)
  int p = blockIdx.x * 64 + sRow;
  int hw = Hout * Wout;
  int n = p / hw;
  int rem = p - n * hw;
  int oh = rem / Wout;
  int ow = rem - oh * Wout;
  const half_t* xb = xin + ((size_t)(n * Hin + oh * S) * Win + ow * S) * CIN;
  half_t* ldsAw = &lds[wid * 512];
  half_t* ldsBw = &lds[2048 + wid * 512];
  // fragment read offsets
  const int fr = lane & 15, fc = lane >> 4;
  const int r0 = (wid & 1) * 32, c0 = (wid >> 1) * 32;
  const int sw = (fc ^ (fr & 3)) * 8;
  const int ia0 = (r0 + fr) * 32 + sw;
  const int ia1 = (r0 + 16 + fr) * 32 + sw;
  const int ib0 = 2048 + (c0 + fr) * 32 + sw;
  const int ib1 = 2048 + (c0 + 16 + fr) * 32 + sw;

  f32x4 acc00 = {0.f, 0.f, 0.f, 0.f};
  f32x4 acc01 = acc00, acc10 = acc00, acc11 = acc00;

  for (int kt = 0; kt < K; kt += 32) {
    int kg = kt + sSwz * 8;
    int ci = kg & (CIN - 1);
    int tap = kg >> LOG2CIN;
    int kh = tap / KW, kw = tap - kh * KW;
    const half_t* gB = xb + (kh * Win + kw) * CIN + ci;
    GLD(gA, ldsAw);
    GLD(gB, ldsBw);
    gA += 32;
    __syncthreads();  // drains vmcnt: LDS tiles ready
    f16x8 a0 = *(const f16x8*)&lds[ia0];
    f16x8 a1 = *(const f16x8*)&lds[ia1];
    f16x8 b0 = *(const f16x8*)&lds[ib0];
    f16x8 b1 = *(const f16x8*)&lds[ib1];
    acc00 = __builtin_amdgcn_mfma_f32_16x16x32_f16(a0, b0, acc00, 0, 0, 0);
    acc01 = __builtin_amdgcn_mfma_f32_16x16x32_f16(a0, b1, acc01, 0, 0, 0);
    acc10 = __builtin_amdgcn_mfma_f32_16x16x32_f16(a1, b0, acc10, 0, 0, 0);
    acc11 = __builtin_amdgcn_mfma_f32_16x16x32_f16(a1, b1, acc11, 0, 0, 0);
    __syncthreads();  // reads done before next tile overwrites LDS
  }

  // epilogue: D col=lane&15 (px), row=(lane>>4)*4+j (co)
  float* outf = (float*)outp;
  half_t* outh = (half_t*)outp;
#pragma unroll
  for (int am = 0; am < 2; ++am) {
#pragma unroll
    for (int bn = 0; bn < 2; ++bn) {
      f32x4 a = am == 0 ? (bn == 0 ? acc00 : acc01) : (bn == 0 ? acc10 : acc11);
      int co = blockIdx.y * 64 + r0 + am * 16 + fc * 4;
      int px = blockIdx.x * 64 + c0 + bn * 16 + fr;
      f32x4 bb = *(const f32x4*)&bias[co];
      f32x4 v;
#pragma unroll
      for (int j = 0; j < 4; ++j) {
        float t = a[j] + bb[j];
        v[j] = LEAKY(t, slope);
      }
      size_t o = (size_t)px * Cout + co;
      if (OUTF32) {
        *(f32x4*)&outf[o] = v;
      } else {
        f16x4 hv;
#pragma unroll
        for (int j = 0; j < 4; ++j) hv[j] = f2h(v[j]);
        *(f16x4*)&outh[o] = hv;
      }
    }
  }
}

// ---------------- FC (in [B,K] @ wT [K,N] + bias, act) ----------------
template <int BB>
__global__ void fc_act(const float* __restrict__ in, const float* __restrict__ wT,
                       const float* __restrict__ bias, float* __restrict__ out,
                       int Brows, int K, int N, int act, float slope) {
  int idx = blockIdx.x * blockDim.x + threadIdx.x;
  int nb = Brows / BB;
  if (idx >= nb * N) return;
  int j = idx % N;
  int b0 = (idx / N) * BB;
  float acc[BB];
  float bj = bias[j];
#pragma unroll
  for (int i = 0; i < BB; ++i) acc[i] = bj;
  const float* ip = in + b0 * K;
  for (int k = 0; k < K; ++k) {
    float wv = wT[k * N + j];
#pragma unroll
    for (int i = 0; i < BB; ++i) acc[i] = fmaf(ip[i * K + k], wv, acc[i]);
  }
#pragma unroll
  for (int i = 0; i < BB; ++i) {
    float v = acc[i];
    if (act == 1) v = LEAKY(v, slope);
    else if (act == 2) v = sig_(v);
    out[(b0 + i) * N + j] = v;
  }
}

// ---------------- fused LSTM layer step ----------------
template <int BB>
__global__ __launch_bounds__(256) void lstm_step(
    const float* __restrict__ base, const float* __restrict__ bias,
    const float* __restrict__ inA, const float* __restrict__ wAT,
    const float* __restrict__ inB, const float* __restrict__ wBT,
    const float* c_in, float* c_out,
    float* __restrict__ h_out, float* __restrict__ ys_out) {
  constexpr int H = 512, G4 = 2048, KS = 4, KCH = H / KS;
  int tid = threadIdx.x;
  int ul = tid & 63;
  int ks = tid >> 6;
  int u = (blockIdx.x & 7) * 64 + ul;
  int b0 = (blockIdx.x >> 3) * BB;

  float acc[4][BB];
#pragma unroll
  for (int g = 0; g < 4; ++g)
#pragma unroll
    for (int i = 0; i < BB; ++i) acc[g][i] = 0.f;

  int k0 = ks * KCH;
  {
    const float* wp = wAT + k0 * G4 + u;
    const float* ip = inA + b0 * H + k0;
    for (int k = 0; k < KCH; ++k) {
      float w0 = wp[0 * H], w1 = wp[1 * H], w2 = wp[2 * H], w3 = wp[3 * H];
      wp += G4;
#pragma unroll
      for (int i = 0; i < BB; ++i) {
        float hv = ip[i * H + k];
        acc[0][i] = fmaf(hv, w0, acc[0][i]);
        acc[1][i] = fmaf(hv, w1, acc[1][i]);
        acc[2][i] = fmaf(hv, w2, acc[2][i]);
        acc[3][i] = fmaf(hv, w3, acc[3][i]);
      }
    }
  }
  if (inB) {
    const float* wp = wBT + k0 * G4 + u;
    const float* ip = inB + b0 * H + k0;
    for (int k = 0; k < KCH; ++k) {
      float w0 = wp[0 * H], w1 = wp[1 * H], w2 = wp[2 * H], w3 = wp[3 * H];
      wp += G4;
#pragma unroll
      for (int i = 0; i < BB; ++i) {
        float hv = ip[i * H + k];
        acc[0][i] = fmaf(hv, w0, acc[0][i]);
        acc[1][i] = fmaf(hv, w1, acc[1][i]);
        acc[2][i] = fmaf(hv, w2, acc[2][i]);
        acc[3][i] = fmaf(hv, w3, acc[3][i]);
      }
    }
  }

  __shared__ float red[KS][4][BB][64];
#pragma unroll
  for (int g = 0; g < 4; ++g)
#pragma unroll
    for (int i = 0; i < BB; ++i) red[ks][g][i][ul] = acc[g][i];
  __syncthreads();

  if (ks == 0) {
#pragma unroll
    for (int i = 0; i < BB; ++i) {
      int b = b0 + i;
      float p[4];
#pragma unroll
      for (int g = 0; g < 4; ++g) {
        float s = red[0][g][i][ul] + red[1][g][i][ul] + red[2][g][i][ul] + red[3][g][i][ul];
        s += base ? base[b * G4 + g * H + u] : bias[g * H + u];
        p[g] = s;
      }
      float cprev = c_in[b * H + u];
      float ig = sig_(p[0]);
      float fg = sig_(p[1]);
      float gg = tanhf(p[2]);
      float og = sig_(p[3]);
      float cn = fg * cprev + ig * gg;
      float hn = og * tanhf(cn);
      c_out[b * H + u] = cn;
      h_out[b * H + u] = hn;
      if (ys_out) ys_out[b * H + u] = hn;
    }
  }
}

// ---------------- launch ----------------
extern "C" void kernel_launch(void* const* d_in, const int* in_sizes, int n_in,
                              void* d_out, int out_size, void* d_ws, size_t ws_size,
                              hipStream_t stream) {
  const float* x   = (const float*)d_in[0];
  const float* w1  = (const float*)d_in[1];  const float* b1 = (const float*)d_in[2];
  const float* w2  = (const float*)d_in[3];  const float* b2 = (const float*)d_in[4];
  const float* w3  = (const float*)d_in[5];  const float* b3 = (const float*)d_in[6];
  const float* w4  = (const float*)d_in[7];  const float* b4 = (const float*)d_in[8];
  const float* w5  = (const float*)d_in[9];  const float* b5 = (const float*)d_in[10];
  const float* wih0 = (const float*)d_in[11]; const float* whh0 = (const float*)d_in[12];
  const float* bih0 = (const float*)d_in[13]; const float* bhh0 = (const float*)d_in[14];
  const float* wih1 = (const float*)d_in[15]; const float* whh1 = (const float*)d_in[16];
  const float* bih1 = (const float*)d_in[17]; const float* bhh1 = (const float*)d_in[18];
  const float* fw1 = (const float*)d_in[19]; const float* fb1 = (const float*)d_in[20];
  const float* fw2 = (const float*)d_in[21]; const float* fb2 = (const float*)d_in[22];
  float* out = (float*)d_out;

  // ---- workspace layout ----
  float* F = (float*)d_ws;
  float* wih0T = F;                        // 1048576
  float* whh0T = wih0T + 1048576;          // 1048576
  float* wih1T = whh0T + 1048576;          // 1048576
  float* whh1T = wih1T + 1048576;          // 1048576
  float* fw1T  = whh1T + 1048576;          // 262144
  float* fw2T  = fw1T + 262144;            // 6656
  float* bg0   = fw2T + 6656;              // 2048
  float* bg1   = bg0 + 2048;               // 2048
  float* xw0   = bg1 + 2048;               // 262144
  float* h0a   = xw0 + 262144;             // 6 x 65536 (h0a,h0b,h1a,h1b,c0,c1)
  float* h0b   = h0a + 65536;
  float* h1a   = h0b + 65536;
  float* h1b   = h1a + 65536;
  float* c0    = h1b + 65536;
  float* c1    = c0 + 65536;
  // fp16 area:
  half_t* U = (half_t*)(c1 + 65536);       // byte off 20,490,240 (256-aligned)
  half_t* xpad = U;                        // 5,017,600  [A4 overlays later]
  half_t* BUF1 = xpad + 5017600;           // 8,388,608  [A1 -> A3 -> f32 feat/ys/fc1o]
  half_t* BUF2 = BUF1 + 8388608;           // 2,768,896  [A2]
  half_t* w1r  = BUF2 + 2768896;           // 26,624
  half_t* w2r  = w1r + 26624;              // 401,408
  half_t* w3r  = w2r + 401408;             // 819,200
  half_t* w4r  = w3r + 819200;             // 3,276,800
  half_t* w5r  = w4r + 3276800;            // 6,553,600
  // total = 74,995,712 bytes

  half_t* A1 = BUF1;    // [128,32,32,64] NHWC fp16
  half_t* A2 = BUF2;    // [128,13,13,128]
  half_t* A3 = BUF1;    // [128,9,9,256]   (A1 dead)
  half_t* A4 = xpad;    // [128,5,5,512]   (xpad dead)
  float* feat = (float*)BUF1;               // [128,512] f32 (A3 dead)
  float* ys   = (float*)(BUF1 + 131072);    // [20*128,512] f32
  float* fc1o = (float*)(BUF1 + 131072 + 2621440);

  dim3 blk(256);

  // ---- prep: LSTM/FC weights (f32), conv weights/input (fp16) ----
  transpose_f32<<<4096, blk, 0, stream>>>(wih0, wih0T, 2048, 512);
  transpose_f32<<<4096, blk, 0, stream>>>(whh0, whh0T, 2048, 512);
  transpose_f32<<<4096, blk, 0, stream>>>(wih1, wih1T, 2048, 512);
  transpose_f32<<<4096, blk, 0, stream>>>(whh1, whh1T, 2048, 512);
  transpose_f32<<<1024, blk, 0, stream>>>(fw1, fw1T, 512, 512);
  transpose_f32<<<26, blk, 0, stream>>>(fw2, fw2T, 13, 512);
  add_pair_f32<<<8, blk, 0, stream>>>(bih0, bhh0, bg0, 2048);
  add_pair_f32<<<8, blk, 0, stream>>>(bih1, bhh1, bg1, 2048);
  zero_f32<<<1536, blk, 0, stream>>>(h0a, 393216);

  pad_x_kernel<<<19600, blk, 0, stream>>>(x, xpad);
  reorder_w1_kernel<<<104, blk, 0, stream>>>(w1, w1r);
  reorder_w_kernel<<<1568, blk, 0, stream>>>(w2, w2r, 401408, 3136, 7, 7, 6);
  reorder_w_kernel<<<3200, blk, 0, stream>>>(w3, w3r, 819200, 3200, 5, 5, 7);
  reorder_w_kernel<<<12800, blk, 0, stream>>>(w4, w4r, 3276800, 6400, 5, 5, 8);
  reorder_w_kernel<<<25600, blk, 0, stream>>>(w5, w5r, 6553600, 12800, 5, 5, 9);

  // ---- conv stack (fp16 MFMA, leaky 0.2) ----
  conv_mfma<7, 2, 3, false><<<dim3(2048, 1), blk, 0, stream>>>(
      xpad, w1r, b1, A1, 70, 70, 32, 32, 64, 416, 0.2f);
  conv_mfma<7, 2, 6, false><<<dim3(338, 2), blk, 0, stream>>>(
      A1, w2r, b2, A2, 32, 32, 13, 13, 128, 3136, 0.2f);
  conv_mfma<5, 1, 7, false><<<dim3(162, 4), blk, 0, stream>>>(
      A2, w3r, b3, A3, 13, 13, 9, 9, 256, 3200, 0.2f);
  conv_mfma<5, 1, 8, false><<<dim3(50, 8), blk, 0, stream>>>(
      A3, w4r, b4, A4, 9, 9, 5, 5, 512, 6400, 0.2f);
  conv_mfma<5, 1, 9, true><<<dim3(2, 8), blk, 0, stream>>>(
      A4, w5r, b5, feat, 5, 5, 1, 1, 512, 12800, 0.2f);

  // xW0 = feat @ wih0.T + (bih0+bhh0)
  fc_act<8><<<128, blk, 0, stream>>>(feat, wih0T, bg0, xw0, 128, 512, 2048, 0, 0.f);

  // 2-layer LSTM, 20 steps
  float* h0buf[2] = {h0a, h0b};
  float* h1buf[2] = {h1a, h1b};
  for (int t = 0; t < 20; ++t) {
    int p = t & 1;
    lstm_step<4><<<256, blk, 0, stream>>>(xw0, nullptr, h0buf[p], whh0T, nullptr, nullptr,
                                          c0, c0, h0buf[p ^ 1], nullptr);
    lstm_step<4><<<256, blk, 0, stream>>>(nullptr, bg1, h0buf[p ^ 1], wih1T, h1buf[p], whh1T,
                                          c1, c1, h1buf[p ^ 1], ys + t * 65536);
  }

  // FC head
  fc_act<8><<<640, blk, 0, stream>>>(ys, fw1T, fb1, fc1o, 2560, 512, 512, 1, 0.01f);
  fc_act<1><<<130, blk, 0, stream>>>(fc1o, fw2T, fb2, out, 2560, 512, 13, 2, 0.f);
}

// Round 4
// 716.953 us; speedup vs baseline: 14.2025x; 2.4628x over previous
//
#include <hip/hip_runtime.h>
#include <math.h>

typedef _Float16 half_t;
typedef __attribute__((ext_vector_type(8))) _Float16 f16x8;
typedef __attribute__((ext_vector_type(4))) _Float16 f16x4;
typedef __attribute__((ext_vector_type(4))) float f32x4;

#define LEAKY(v, s) ((v) >= 0.f ? (v) : (s) * (v))

__device__ __forceinline__ float sig_(float x) { return 1.f / (1.f + expf(-x)); }
__device__ __forceinline__ half_t f2h(float f) { return (half_t)f; }  // RNE v_cvt_f16_f32

#define GLD(gp, lp)                                              \
  __builtin_amdgcn_global_load_lds(                              \
      (const __attribute__((address_space(1))) void*)(gp),       \
      (__attribute__((address_space(3))) void*)(lp), 16, 0, 0)

// ---------------- utility / prep kernels ----------------
__global__ void add_pair_f32(const float* __restrict__ a, const float* __restrict__ b,
                             float* __restrict__ out, int n) {
  int i = blockIdx.x * blockDim.x + threadIdx.x;
  if (i < n) out[i] = a[i] + b[i];
}

__global__ void zero_f32(float* p, int n) {
  int i = blockIdx.x * blockDim.x + threadIdx.x;
  if (i < n) p[i] = 0.f;
}

__global__ void cast_f16(const float* __restrict__ in, half_t* __restrict__ out, int n) {
  int i = blockIdx.x * blockDim.x + threadIdx.x;
  if (i < n) out[i] = f2h(in[i]);
}

// x [128,3,64,64] f32 -> xpad [128,70,70,8] fp16, spatial pad 3, channel pad to 8
__global__ void pad_x_kernel(const float* __restrict__ x, half_t* __restrict__ xp) {
  int i = blockIdx.x * blockDim.x + threadIdx.x;
  if (i >= 128 * 70 * 70 * 8) return;
  int c = i & 7;
  int t = i >> 3;
  int iw = t % 70; t /= 70;
  int ih = t % 70;
  int n = t / 70;
  float v = 0.f;
  if (c < 3 && ih >= 3 && ih < 67 && iw >= 3 && iw < 67)
    v = x[((n * 3 + c) * 64 + (ih - 3)) * 64 + (iw - 3)];
  xp[i] = f2h(v);
}

// w1 [64,3,7,7] -> [64][416] fp16; kg=(tap<<3)+ci, taps 0..48 valid ci 0..2, rest 0
__global__ void reorder_w1_kernel(const float* __restrict__ w, half_t* __restrict__ wr) {
  int i = blockIdx.x * blockDim.x + threadIdx.x;
  if (i >= 64 * 416) return;
  int kg = i % 416;
  int co = i / 416;
  int ci = kg & 7;
  int tap = kg >> 3;
  float v = 0.f;
  if (tap < 49 && ci < 3) {
    int kh = tap / 7, kw = tap % 7;
    v = w[((co * 3 + ci) * 7 + kh) * 7 + kw];
  }
  wr[i] = f2h(v);
}

// w [Cout,Cin,KH,KW] f32 -> wr [Cout][(kh*KW+kw)*Cin+ci] fp16
__global__ void reorder_w_kernel(const float* __restrict__ w, half_t* __restrict__ wr,
                                 int total, int K, int KW, int KH, int log2Cin) {
  int i = blockIdx.x * blockDim.x + threadIdx.x;
  if (i >= total) return;
  int kg = i % K;
  int co = i / K;
  int Cin = 1 << log2Cin;
  int ci = kg & (Cin - 1);
  int tap = kg >> log2Cin;
  int kh = tap / KW, kw = tap - kh * KW;
  wr[i] = f2h(w[(((size_t)co * Cin + ci) * KH + kh) * KW + kw]);
}

// whh0 [2048,512] -> wcat0 [2048][512] fp16, row r=u*4+g <- whh0 row g*512+u
__global__ void build_wcat0(const float* __restrict__ whh, half_t* __restrict__ out) {
  int i = blockIdx.x * blockDim.x + threadIdx.x;
  if (i >= 2048 * 512) return;
  int r = i >> 9, k = i & 511;
  int u = r >> 2, g = r & 3;
  out[i] = f2h(whh[(g * 512 + u) * 512 + k]);
}

// wcat1 [2048][1024] fp16, row r=u*4+g = [wih1 row | whh1 row] of source row g*512+u
__global__ void build_wcat1(const float* __restrict__ wih, const float* __restrict__ whh,
                            half_t* __restrict__ out) {
  int i = blockIdx.x * blockDim.x + threadIdx.x;
  if (i >= 2048 * 1024) return;
  int r = i >> 10, k = i & 1023;
  int u = r >> 2, g = r & 3;
  int row = g * 512 + u;
  out[i] = f2h(k < 512 ? wih[row * 512 + k] : whh[row * 512 + (k - 512)]);
}

// ---------------- implicit-im2col fp16 MFMA conv / GEMM ----------------
// C[co][px] = sum_k W[co][k] * X[k][px]. Tile 64x64x32, 4 waves 2x2 16x16x32 MFMA.
// 2-phase: stage tile t+1 (global_load_lds, dbuf) before compute of tile t;
// one __syncthreads per iter. K-split via blockIdx.z (ktiles per z).
// OUTMODE: 0 = fp16 out + bias + leaky; 1 = f32 out + bias + leaky;
//          2 = f32 raw partial at z-offset (no bias).
template <int KW, int S, int LOG2CIN, int OUTMODE>
__global__ __launch_bounds__(256) void conv_mfma(
    const half_t* __restrict__ xin, const half_t* __restrict__ wr,
    const float* __restrict__ bias, void* __restrict__ outp,
    int Hin, int Win, int Hout, int Wout, int Cout, int K, int ktiles, float slope) {
  constexpr int CIN = 1 << LOG2CIN;
  __shared__ half_t lds[2][4096];  // per buf: A [64][32] at 0, B [64][32] at 2048
  const int tid = threadIdx.x;
  const int lane = tid & 63, wid = tid >> 6;
  const int sRow = tid >> 2, sCh = tid & 3;
  const int sSwz = sCh ^ (sRow & 3);
  const int kt0 = blockIdx.z * ktiles;
  const half_t* gArow = wr + (size_t)(blockIdx.y * 64 + sRow) * K + sSwz * 8;
  // B pixel decompose (invariant over K)
  int p = blockIdx.x * 64 + sRow;
  int hw = Hout * Wout;
  int n = p / hw;
  int rem = p - n * hw;
  int oh = rem / Wout;
  int ow = rem - oh * Wout;
  const half_t* xb = xin + ((size_t)(n * Hin + oh * S) * Win + ow * S) * CIN;
  // fragment read offsets (within one buffer)
  const int fr = lane & 15, fc = lane >> 4;
  const int r0 = (wid & 1) * 32, c0 = (wid >> 1) * 32;
  const int sw = (fc ^ (fr & 3)) * 8;
  const int ia0 = (r0 + fr) * 32 + sw;
  const int ia1 = (r0 + 16 + fr) * 32 + sw;
  const int ib0 = 2048 + (c0 + fr) * 32 + sw;
  const int ib1 = 2048 + (c0 + 16 + fr) * 32 + sw;

  auto stage = [&](int t, int buf) {
    GLD(gArow + (size_t)(kt0 + t) * 32, &lds[buf][wid * 512]);
    int kg = (kt0 + t) * 32 + sSwz * 8;
    int ci = kg & (CIN - 1);
    int tap = kg >> LOG2CIN;
    int kh = tap / KW, kw = tap - kh * KW;
    GLD(xb + (kh * Win + kw) * CIN + ci, &lds[buf][2048 + wid * 512]);
  };

  f32x4 acc00 = {0.f, 0.f, 0.f, 0.f};
  f32x4 acc01 = acc00, acc10 = acc00, acc11 = acc00;

  stage(0, 0);
  __syncthreads();
  for (int t = 0; t < ktiles; ++t) {
    int cur = t & 1;
    if (t + 1 < ktiles) stage(t + 1, cur ^ 1);
    const half_t* L = &lds[cur][0];
    f16x8 a0 = *(const f16x8*)&L[ia0];
    f16x8 a1 = *(const f16x8*)&L[ia1];
    f16x8 b0 = *(const f16x8*)&L[ib0];
    f16x8 b1 = *(const f16x8*)&L[ib1];
    acc00 = __builtin_amdgcn_mfma_f32_16x16x32_f16(a0, b0, acc00, 0, 0, 0);
    acc01 = __builtin_amdgcn_mfma_f32_16x16x32_f16(a0, b1, acc01, 0, 0, 0);
    acc10 = __builtin_amdgcn_mfma_f32_16x16x32_f16(a1, b0, acc10, 0, 0, 0);
    acc11 = __builtin_amdgcn_mfma_f32_16x16x32_f16(a1, b1, acc11, 0, 0, 0);
    __syncthreads();
  }

  // epilogue: D col=lane&15 (px), row=(lane>>4)*4+j (co)
#pragma unroll
  for (int am = 0; am < 2; ++am) {
#pragma unroll
    for (int bn = 0; bn < 2; ++bn) {
      f32x4 a = am == 0 ? (bn == 0 ? acc00 : acc01) : (bn == 0 ? acc10 : acc11);
      int co = blockIdx.y * 64 + r0 + am * 16 + fc * 4;
      int px = blockIdx.x * 64 + c0 + bn * 16 + fr;
      size_t o = (size_t)px * Cout + co;
      if (OUTMODE == 2) {
        float* pb = (float*)outp + (size_t)blockIdx.z * ((size_t)gridDim.x * 64 * Cout);
        *(f32x4*)&pb[o] = a;
      } else {
        f32x4 bb = *(const f32x4*)&bias[co];
        f32x4 v;
#pragma unroll
        for (int j = 0; j < 4; ++j) {
          float t = a[j] + bb[j];
          v[j] = LEAKY(t, slope);
        }
        if (OUTMODE == 1) {
          *(f32x4*)&((float*)outp)[o] = v;
        } else {
          f16x4 hv;
#pragma unroll
          for (int j = 0; j < 4; ++j) hv[j] = f2h(v[j]);
          *(f16x4*)&((half_t*)outp)[o] = hv;
        }
      }
    }
  }
}

// reduce conv5 K-split partials: feat[i] = f2h(leaky(sum_z pb[z][i] + bias[i&511]))
__global__ void finalize5(const float* __restrict__ pb, const float* __restrict__ bias,
                          half_t* __restrict__ feat) {
  int i = blockIdx.x * blockDim.x + threadIdx.x;
  if (i >= 65536) return;
  float s = bias[i & 511];
#pragma unroll 5
  for (int z = 0; z < 25; ++z) s += pb[z * 65536 + i];
  feat[i] = f2h(LEAKY(s, 0.2f));
}

// ---------------- fused LSTM layer step (fp16 MFMA + gates) ----------------
// pre rows reordered: wcat row r = u*4+g. C[r][b]: each thread's f32x4 = 4 gates
// of one (u,b). KT=16: K=512 (B from hA). KT=32: K=1024 (B = [hA | hB]).
template <int KT>
__global__ __launch_bounds__(256) void lstm_mfma(
    const half_t* __restrict__ hA, const half_t* __restrict__ hB,
    const half_t* __restrict__ wcat,
    const float* __restrict__ base,   // xw0 [128][2048] (g*512+u) or nullptr
    const float* __restrict__ bias,   // bg1 [2048] (g*512+u) or nullptr
    float* __restrict__ c, half_t* __restrict__ hout, half_t* __restrict__ ysout) {
  constexpr int K = KT * 32;
  __shared__ half_t lds[2][4096];
  const int tid = threadIdx.x;
  const int lane = tid & 63, wid = tid >> 6;
  const int sRow = tid >> 2, sCh = tid & 3;
  const int sSwz = sCh ^ (sRow & 3);
  const half_t* gArow = wcat + (size_t)(blockIdx.y * 64 + sRow) * K + sSwz * 8;
  const int bb = blockIdx.x * 64 + sRow;
  const int fr = lane & 15, fc = lane >> 4;
  const int r0 = (wid & 1) * 32, c0 = (wid >> 1) * 32;
  const int sw = (fc ^ (fr & 3)) * 8;
  const int ia0 = (r0 + fr) * 32 + sw;
  const int ia1 = (r0 + 16 + fr) * 32 + sw;
  const int ib0 = 2048 + (c0 + fr) * 32 + sw;
  const int ib1 = 2048 + (c0 + 16 + fr) * 32 + sw;

  auto stage = [&](int t, int buf) {
    GLD(gArow + t * 32, &lds[buf][wid * 512]);
    int kg = t * 32 + sSwz * 8;
    const half_t* hsrc = (t < 16) ? hA : hB;  // uniform per tile (32 | 512)
    GLD(hsrc + bb * 512 + (kg & 511), &lds[buf][2048 + wid * 512]);
  };

  f32x4 acc00 = {0.f, 0.f, 0.f, 0.f};
  f32x4 acc01 = acc00, acc10 = acc00, acc11 = acc00;

  stage(0, 0);
  __syncthreads();
  for (int t = 0; t < KT; ++t) {
    int cur = t & 1;
    if (t + 1 < KT) stage(t + 1, cur ^ 1);
    const half_t* L = &lds[cur][0];
    f16x8 a0 = *(const f16x8*)&L[ia0];
    f16x8 a1 = *(const f16x8*)&L[ia1];
    f16x8 b0 = *(const f16x8*)&L[ib0];
    f16x8 b1 = *(const f16x8*)&L[ib1];
    acc00 = __builtin_amdgcn_mfma_f32_16x16x32_f16(a0, b0, acc00, 0, 0, 0);
    acc01 = __builtin_amdgcn_mfma_f32_16x16x32_f16(a0, b1, acc01, 0, 0, 0);
    acc10 = __builtin_amdgcn_mfma_f32_16x16x32_f16(a1, b0, acc10, 0, 0, 0);
    acc11 = __builtin_amdgcn_mfma_f32_16x16x32_f16(a1, b1, acc11, 0, 0, 0);
    __syncthreads();
  }

#pragma unroll
  for (int am = 0; am < 2; ++am) {
#pragma unroll
    for (int bn = 0; bn < 2; ++bn) {
      f32x4 a = am == 0 ? (bn == 0 ? acc00 : acc01) : (bn == 0 ? acc10 : acc11);
      int Rb = blockIdx.y * 64 + r0 + am * 16 + fc * 4;  // row base, gate = j
      int u = Rb >> 2;
      int b = blockIdx.x * 64 + c0 + bn * 16 + fr;
      float p[4];
#pragma unroll
      for (int j = 0; j < 4; ++j) {
        float s = a[j];
        s += base ? base[b * 2048 + j * 512 + u] : bias[j * 512 + u];
        p[j] = s;
      }
      int ci = b * 512 + u;
      float cprev = c[ci];
      float ig = sig_(p[0]);
      float fg = sig_(p[1]);
      float gg = tanhf(p[2]);
      float og = sig_(p[3]);
      float cn = fg * cprev + ig * gg;
      float hn = og * tanhf(cn);
      c[ci] = cn;
      hout[ci] = f2h(hn);
      if (ysout) ysout[ci] = f2h(hn);
    }
  }
}

// ---------------- final FC: sigmoid(fc1o @ fw2.T + fb2), [2560,13] ----------------
__global__ void fc2_sigmoid(const half_t* __restrict__ in, const float* __restrict__ w,
                            const float* __restrict__ b, float* __restrict__ out) {
  int idx = blockIdx.x * blockDim.x + threadIdx.x;
  if (idx >= 2560 * 13) return;
  int j = idx % 13, r = idx / 13;
  const half_t* ip = in + (size_t)r * 512;
  const float* wp = w + j * 512;
  float s = b[j];
  for (int k = 0; k < 512; k += 8) {
    f16x8 hv = *(const f16x8*)&ip[k];
#pragma unroll
    for (int q = 0; q < 8; ++q) s = fmaf((float)hv[q], wp[k + q], s);
  }
  out[idx] = sig_(s);
}

// ---------------- launch ----------------
extern "C" void kernel_launch(void* const* d_in, const int* in_sizes, int n_in,
                              void* d_out, int out_size, void* d_ws, size_t ws_size,
                              hipStream_t stream) {
  const float* x   = (const float*)d_in[0];
  const float* w1  = (const float*)d_in[1];  const float* b1 = (const float*)d_in[2];
  const float* w2  = (const float*)d_in[3];  const float* b2 = (const float*)d_in[4];
  const float* w3  = (const float*)d_in[5];  const float* b3 = (const float*)d_in[6];
  const float* w4  = (const float*)d_in[7];  const float* b4 = (const float*)d_in[8];
  const float* w5  = (const float*)d_in[9];  const float* b5 = (const float*)d_in[10];
  const float* wih0 = (const float*)d_in[11]; const float* whh0 = (const float*)d_in[12];
  const float* bih0 = (const float*)d_in[13]; const float* bhh0 = (const float*)d_in[14];
  const float* wih1 = (const float*)d_in[15]; const float* whh1 = (const float*)d_in[16];
  const float* bih1 = (const float*)d_in[17]; const float* bhh1 = (const float*)d_in[18];
  const float* fw1 = (const float*)d_in[19]; const float* fb1 = (const float*)d_in[20];
  const float* fw2 = (const float*)d_in[21]; const float* fb2 = (const float*)d_in[22];
  float* out = (float*)d_out;

  // ---- workspace layout (total ~65.5 MB) ----
  float* bg0 = (float*)d_ws;               // 2048
  float* bg1 = bg0 + 2048;                 // 2048
  float* xw0 = bg1 + 2048;                 // 262144
  float* c0  = xw0 + 262144;               // 65536
  float* c1  = c0 + 65536;                 // 65536  (c0,c1,h* zeroed together)
  half_t* h0a = (half_t*)(c1 + 65536);     // 65536 h each
  half_t* h0b = h0a + 65536;
  half_t* h1a = h0b + 65536;
  half_t* h1b = h1a + 65536;
  half_t* U    = h1b + 65536;
  half_t* xpad = U;                        // 5,017,600   [A4 overlays]
  half_t* BUF1 = xpad + 5017600;           // 8,388,608   [A1 -> A3 -> feat+pbuf5]
  half_t* BUF2 = BUF1 + 8388608;           // 2,768,896   [A2 -> ys+fc1o]
  half_t* w1r  = BUF2 + 2768896;           // 26,624
  half_t* w2r  = w1r + 26624;              // 401,408
  half_t* w3r  = w2r + 401408;             // 819,200
  half_t* w4r  = w3r + 819200;             // 3,276,800
  half_t* w5r  = w4r + 3276800;            // 6,553,600
  half_t* wih0h  = w5r + 6553600;          // 1,048,576
  half_t* wcat0h = wih0h + 1048576;        // 1,048,576
  half_t* wcat1h = wcat0h + 1048576;       // 2,097,152
  half_t* fw1h   = wcat1h + 2097152;       // 262,144

  half_t* A1 = BUF1;                       // [128,32,32,64] NHWC fp16
  half_t* A2 = BUF2;                       // [128,13,13,128]
  half_t* A3 = BUF1;                       // [128,9,9,256]
  half_t* A4 = xpad;                       // [128,5,5,512]
  half_t* feat = BUF1;                     // [128,512] fp16 (A3 dead)
  float* pbuf5 = (float*)(BUF1 + 65536);   // 25 x 65536 f32 partials (A3 dead)
  half_t* ys   = BUF2;                     // [2560,512] fp16 (A2 dead)
  half_t* fc1o = BUF2 + 1310720;           // [2560,512] fp16

  dim3 blk(256);

  // ---- prep ----
  add_pair_f32<<<8, blk, 0, stream>>>(bih0, bhh0, bg0, 2048);
  add_pair_f32<<<8, blk, 0, stream>>>(bih1, bhh1, bg1, 2048);
  zero_f32<<<1024, blk, 0, stream>>>(c0, 262144);  // c0,c1 + h0a,h0b,h1a,h1b
  pad_x_kernel<<<19600, blk, 0, stream>>>(x, xpad);
  reorder_w1_kernel<<<104, blk, 0, stream>>>(w1, w1r);
  reorder_w_kernel<<<1568, blk, 0, stream>>>(w2, w2r, 401408, 3136, 7, 7, 6);
  reorder_w_kernel<<<3200, blk, 0, stream>>>(w3, w3r, 819200, 3200, 5, 5, 7);
  reorder_w_kernel<<<12800, blk, 0, stream>>>(w4, w4r, 3276800, 6400, 5, 5, 8);
  reorder_w_kernel<<<25600, blk, 0, stream>>>(w5, w5r, 6553600, 12800, 5, 5, 9);
  cast_f16<<<4096, blk, 0, stream>>>(wih0, wih0h, 1048576);
  cast_f16<<<1024, blk, 0, stream>>>(fw1, fw1h, 262144);
  build_wcat0<<<4096, blk, 0, stream>>>(whh0, wcat0h);
  build_wcat1<<<8192, blk, 0, stream>>>(wih1, whh1, wcat1h);

  // ---- conv stack (fp16 MFMA, leaky 0.2) ----
  conv_mfma<7, 2, 3, 0><<<dim3(2048, 1, 1), blk, 0, stream>>>(
      xpad, w1r, b1, A1, 70, 70, 32, 32, 64, 416, 13, 0.2f);
  conv_mfma<7, 2, 6, 0><<<dim3(338, 2, 1), blk, 0, stream>>>(
      A1, w2r, b2, A2, 32, 32, 13, 13, 128, 3136, 98, 0.2f);
  conv_mfma<5, 1, 7, 0><<<dim3(162, 4, 1), blk, 0, stream>>>(
      A2, w3r, b3, A3, 13, 13, 9, 9, 256, 3200, 100, 0.2f);
  conv_mfma<5, 1, 8, 0><<<dim3(50, 8, 1), blk, 0, stream>>>(
      A3, w4r, b4, A4, 9, 9, 5, 5, 512, 6400, 200, 0.2f);
  // conv5: K-split x25 into f32 partials, then finalize -> feat fp16
  conv_mfma<5, 1, 9, 2><<<dim3(2, 8, 25), blk, 0, stream>>>(
      A4, w5r, b5, pbuf5, 5, 5, 1, 1, 512, 12800, 16, 0.2f);
  finalize5<<<256, blk, 0, stream>>>(pbuf5, b5, feat);

  // xw0 = feat @ wih0.T + bg0   [128][2048], f32, identity act (slope=1)
  conv_mfma<1, 1, 9, 1><<<dim3(2, 32, 1), blk, 0, stream>>>(
      feat, wih0h, bg0, xw0, 1, 1, 1, 1, 2048, 512, 16, 1.0f);

  // ---- 2-layer LSTM, 20 steps (fp16 MFMA, fused gates) ----
  half_t* h0buf[2] = {h0a, h0b};
  half_t* h1buf[2] = {h1a, h1b};
  for (int t = 0; t < 20; ++t) {
    int p = t & 1;
    lstm_mfma<16><<<dim3(2, 32), blk, 0, stream>>>(
        h0buf[p], h0buf[p], wcat0h, xw0, nullptr, c0, h0buf[p ^ 1], nullptr);
    lstm_mfma<32><<<dim3(2, 32), blk, 0, stream>>>(
        h0buf[p ^ 1], h1buf[p], wcat1h, nullptr, bg1, c1, h1buf[p ^ 1],
        ys + (size_t)t * 65536);
  }

  // ---- FC head ----
  // fc1o = leaky(ys @ fw1.T + fb1, 0.01)  [2560][512] fp16, via MFMA
  conv_mfma<1, 1, 9, 0><<<dim3(40, 8, 1), blk, 0, stream>>>(
      ys, fw1h, fb1, fc1o, 1, 1, 1, 1, 512, 512, 16, 0.01f);
  // out = sigmoid(fc1o @ fw2.T + fb2)  [2560][13] f32
  fc2_sigmoid<<<130, blk, 0, stream>>>(fc1o, fw2, fb2, out);
}

// Round 5
// 519.417 us; speedup vs baseline: 19.6037x; 1.3803x over previous
//
#include <hip/hip_runtime.h>
#include <math.h>

typedef _Float16 half_t;
typedef __attribute__((ext_vector_type(8))) _Float16 f16x8;
typedef __attribute__((ext_vector_type(4))) _Float16 f16x4;
typedef __attribute__((ext_vector_type(4))) float f32x4;

#define LEAKY(v, s) ((v) >= 0.f ? (v) : (s) * (v))

__device__ __forceinline__ float sig_(float x) { return 1.f / (1.f + expf(-x)); }
__device__ __forceinline__ half_t f2h(float f) { return (half_t)f; }  // RNE v_cvt_f16_f32

#define GLD(gp, lp)                                              \
  __builtin_amdgcn_global_load_lds(                              \
      (const __attribute__((address_space(1))) void*)(gp),       \
      (__attribute__((address_space(3))) void*)(lp), 16, 0, 0)

// pipeline phase: counted vmcnt (loads stay in flight across barrier), raw barrier
#define PHASE_WAIT(N)                                            \
  asm volatile("s_waitcnt vmcnt(" #N ")" ::: "memory");          \
  __builtin_amdgcn_s_barrier();                                  \
  __builtin_amdgcn_sched_barrier(0)

// ---------------- utility / prep kernels ----------------
__global__ void add_pair_f32(const float* __restrict__ a, const float* __restrict__ b,
                             float* __restrict__ out, int n) {
  int i = blockIdx.x * blockDim.x + threadIdx.x;
  if (i < n) out[i] = a[i] + b[i];
}

__global__ void zero_f32(float* p, int n) {
  int i = blockIdx.x * blockDim.x + threadIdx.x;
  if (i < n) p[i] = 0.f;
}

__global__ void cast_f16(const float* __restrict__ in, half_t* __restrict__ out, int n) {
  int i = blockIdx.x * blockDim.x + threadIdx.x;
  if (i < n) out[i] = f2h(in[i]);
}

// x [128,3,64,64] f32 -> xpad [128,70,70,8] fp16, spatial pad 3, channel pad to 8
__global__ void pad_x_kernel(const float* __restrict__ x, half_t* __restrict__ xp) {
  int i = blockIdx.x * blockDim.x + threadIdx.x;
  if (i >= 128 * 70 * 70 * 8) return;
  int c = i & 7;
  int t = i >> 3;
  int iw = t % 70; t /= 70;
  int ih = t % 70;
  int n = t / 70;
  float v = 0.f;
  if (c < 3 && ih >= 3 && ih < 67 && iw >= 3 && iw < 67)
    v = x[((n * 3 + c) * 64 + (ih - 3)) * 64 + (iw - 3)];
  xp[i] = f2h(v);
}

// w1 [64,3,7,7] -> [64][416] fp16; kg=(tap<<3)+ci, taps 0..48 valid ci 0..2, rest 0
__global__ void reorder_w1_kernel(const float* __restrict__ w, half_t* __restrict__ wr) {
  int i = blockIdx.x * blockDim.x + threadIdx.x;
  if (i >= 64 * 416) return;
  int kg = i % 416;
  int co = i / 416;
  int ci = kg & 7;
  int tap = kg >> 3;
  float v = 0.f;
  if (tap < 49 && ci < 3) {
    int kh = tap / 7, kw = tap % 7;
    v = w[((co * 3 + ci) * 7 + kh) * 7 + kw];
  }
  wr[i] = f2h(v);
}

// w [Cout,Cin,KH,KW] f32 -> wr [Cout][(kh*KW+kw)*Cin+ci] fp16
__global__ void reorder_w_kernel(const float* __restrict__ w, half_t* __restrict__ wr,
                                 int total, int K, int KW, int KH, int log2Cin) {
  int i = blockIdx.x * blockDim.x + threadIdx.x;
  if (i >= total) return;
  int kg = i % K;
  int co = i / K;
  int Cin = 1 << log2Cin;
  int ci = kg & (Cin - 1);
  int tap = kg >> log2Cin;
  int kh = tap / KW, kw = tap - kh * KW;
  wr[i] = f2h(w[(((size_t)co * Cin + ci) * KH + kh) * KW + kw]);
}

// whh0 [2048,512] -> wcat0 [2048][512] fp16, row r=u*4+g <- whh0 row g*512+u
__global__ void build_wcat0(const float* __restrict__ whh, half_t* __restrict__ out) {
  int i = blockIdx.x * blockDim.x + threadIdx.x;
  if (i >= 2048 * 512) return;
  int r = i >> 9, k = i & 511;
  int u = r >> 2, g = r & 3;
  out[i] = f2h(whh[(g * 512 + u) * 512 + k]);
}

// wcat1 [2048][1024] fp16, row r=u*4+g = [wih1 row | whh1 row] of source row g*512+u
__global__ void build_wcat1(const float* __restrict__ wih, const float* __restrict__ whh,
                            half_t* __restrict__ out) {
  int i = blockIdx.x * blockDim.x + threadIdx.x;
  if (i >= 2048 * 1024) return;
  int r = i >> 10, k = i & 1023;
  int u = r >> 2, g = r & 3;
  int row = g * 512 + u;
  out[i] = f2h(k < 512 ? wih[row * 512 + k] : whh[row * 512 + (k - 512)]);
}

// ---------------- implicit-im2col fp16 MFMA conv / GEMM ----------------
// Tile 64x64x32, 4 waves 2x2 16x16x32 MFMA. Depth-4 pipeline, counted vmcnt,
// one raw barrier per K-iter. Chunk swizzle sigma(r)=(r^(r>>2))&3 on both the
// pre-swizzled global source and the ds_read (both-sides rule).
// OUTMODE: 0 fp16+bias+leaky; 1 f32+bias+leaky; 2 f32 raw partial at z-offset.
template <int KW, int S, int LOG2CIN, int OUTMODE>
__global__ __launch_bounds__(256) void conv_mfma(
    const half_t* __restrict__ xin, const half_t* __restrict__ wr,
    const float* __restrict__ bias, void* __restrict__ outp,
    int Hin, int Win, int Hout, int Wout, int Cout, int K, int ktiles, float slope) {
  constexpr int CIN = 1 << LOG2CIN;
  __shared__ half_t lds[4][4096];  // per buf: A [64][32] at 0, B [64][32] at 2048
  const int tid = threadIdx.x;
  const int lane = tid & 63, wid = tid >> 6;
  const int sRow = tid >> 2, sCh = tid & 3;
  const int sSwz = sCh ^ ((sRow ^ (sRow >> 2)) & 3);
  const int kt0 = blockIdx.z * ktiles;
  const half_t* gArow = wr + (size_t)(blockIdx.y * 64 + sRow) * K + sSwz * 8;
  // B pixel decompose (invariant over K)
  int p = blockIdx.x * 64 + sRow;
  int hw = Hout * Wout;
  int n = p / hw;
  int rem = p - n * hw;
  int oh = rem / Wout;
  int ow = rem - oh * Wout;
  const half_t* xb = xin + ((size_t)(n * Hin + oh * S) * Win + ow * S) * CIN;
  // fragment read offsets (within one buffer)
  const int fr = lane & 15, fc = lane >> 4;
  const int r0 = (wid & 1) * 32, c0 = (wid >> 1) * 32;
  const int sw = (fc ^ ((fr ^ (fr >> 2)) & 3)) * 8;
  const int ia0 = (r0 + fr) * 32 + sw;
  const int ia1 = (r0 + 16 + fr) * 32 + sw;
  const int ib0 = 2048 + (c0 + fr) * 32 + sw;
  const int ib1 = 2048 + (c0 + 16 + fr) * 32 + sw;

  auto stage = [&](int t, int buf) {
    GLD(gArow + (size_t)(kt0 + t) * 32, &lds[buf][wid * 512]);
    int kg = (kt0 + t) * 32 + sSwz * 8;
    int ci = kg & (CIN - 1);
    int tap = kg >> LOG2CIN;
    int kh = tap / KW, kw = tap - kh * KW;
    GLD(xb + (kh * Win + kw) * CIN + ci, &lds[buf][2048 + wid * 512]);
  };

  f32x4 acc00 = {0.f, 0.f, 0.f, 0.f};
  f32x4 acc01 = acc00, acc10 = acc00, acc11 = acc00;

  auto compute = [&](int buf) {
    const half_t* L = &lds[buf][0];
    f16x8 a0 = *(const f16x8*)&L[ia0];
    f16x8 a1 = *(const f16x8*)&L[ia1];
    f16x8 b0 = *(const f16x8*)&L[ib0];
    f16x8 b1 = *(const f16x8*)&L[ib1];
    acc00 = __builtin_amdgcn_mfma_f32_16x16x32_f16(a0, b0, acc00, 0, 0, 0);
    acc01 = __builtin_amdgcn_mfma_f32_16x16x32_f16(a0, b1, acc01, 0, 0, 0);
    acc10 = __builtin_amdgcn_mfma_f32_16x16x32_f16(a1, b0, acc10, 0, 0, 0);
    acc11 = __builtin_amdgcn_mfma_f32_16x16x32_f16(a1, b1, acc11, 0, 0, 0);
  };

  stage(0, 0);
  stage(1, 1);
  stage(2, 2);
  int t = 0;
  for (; t < ktiles - 3; ++t) {
    PHASE_WAIT(4);
    stage(t + 3, (t + 3) & 3);
    compute(t & 3);
  }
  PHASE_WAIT(4);
  compute(t & 3);
  ++t;
  PHASE_WAIT(2);
  compute(t & 3);
  ++t;
  PHASE_WAIT(0);
  compute(t & 3);

  // epilogue: D col=lane&15 (px), row=(lane>>4)*4+j (co)
#pragma unroll
  for (int am = 0; am < 2; ++am) {
#pragma unroll
    for (int bn = 0; bn < 2; ++bn) {
      f32x4 a = am == 0 ? (bn == 0 ? acc00 : acc01) : (bn == 0 ? acc10 : acc11);
      int co = blockIdx.y * 64 + r0 + am * 16 + fc * 4;
      int px = blockIdx.x * 64 + c0 + bn * 16 + fr;
      size_t o = (size_t)px * Cout + co;
      if (OUTMODE == 2) {
        float* pb = (float*)outp + (size_t)blockIdx.z * ((size_t)gridDim.x * 64 * Cout);
        *(f32x4*)&pb[o] = a;
      } else {
        f32x4 bb = *(const f32x4*)&bias[co];
        f32x4 v;
#pragma unroll
        for (int j = 0; j < 4; ++j) {
          float tt = a[j] + bb[j];
          v[j] = LEAKY(tt, slope);
        }
        if (OUTMODE == 1) {
          *(f32x4*)&((float*)outp)[o] = v;
        } else {
          f16x4 hv;
#pragma unroll
          for (int j = 0; j < 4; ++j) hv[j] = f2h(v[j]);
          *(f16x4*)&((half_t*)outp)[o] = hv;
        }
      }
    }
  }
}

// reduce conv5 K-split partials: feat[i] = f2h(leaky(sum_z pb[z][i] + bias[i&511]))
__global__ void finalize5(const float* __restrict__ pb, const float* __restrict__ bias,
                          half_t* __restrict__ feat) {
  int i = blockIdx.x * blockDim.x + threadIdx.x;
  if (i >= 65536) return;
  float s = bias[i & 511];
#pragma unroll 5
  for (int z = 0; z < 25; ++z) s += pb[z * 65536 + i];
  feat[i] = f2h(LEAKY(s, 0.2f));
}

// ---------------- fused LSTM step: layer0(t+1) || layer1(t) ----------------
// Both roles depend only on the previous launch's outputs, so they share one
// launch. roles: 1 = l0 only, 2 = l1 only, 3 = both (z=0 l0, z=1 l1).
// wcat row r=u*4+g; each thread's f32x4 = gates i,f,g,o of one (u,b).
__global__ __launch_bounds__(256) void lstm_fused(
    const half_t* __restrict__ h0in, half_t* __restrict__ h0out,
    const half_t* __restrict__ h1in, half_t* __restrict__ h1out,
    const half_t* __restrict__ wcat0, const half_t* __restrict__ wcat1,
    const float* __restrict__ xw0, const float* __restrict__ bg1,
    float* __restrict__ c0, float* __restrict__ c1,
    half_t* __restrict__ ysout, int roles) {
  const bool isL1 = (roles == 2) || (blockIdx.z == 1);
  const int KT = isL1 ? 32 : 16;
  const half_t* wcat = isL1 ? wcat1 : wcat0;
  const half_t* hB = h1in;
  float* c = isL1 ? c1 : c0;
  half_t* hout = isL1 ? h1out : h0out;
  const int K = KT * 32;

  __shared__ half_t lds[4][4096];
  const int tid = threadIdx.x;
  const int lane = tid & 63, wid = tid >> 6;
  const int sRow = tid >> 2, sCh = tid & 3;
  const int sSwz = sCh ^ ((sRow ^ (sRow >> 2)) & 3);
  const half_t* gArow = wcat + (size_t)(blockIdx.y * 64 + sRow) * K + sSwz * 8;
  const int bb = blockIdx.x * 64 + sRow;
  const int fr = lane & 15, fc = lane >> 4;
  const int r0 = (wid & 1) * 32, c0w = (wid >> 1) * 32;
  const int sw = (fc ^ ((fr ^ (fr >> 2)) & 3)) * 8;
  const int ia0 = (r0 + fr) * 32 + sw;
  const int ia1 = (r0 + 16 + fr) * 32 + sw;
  const int ib0 = 2048 + (c0w + fr) * 32 + sw;
  const int ib1 = 2048 + (c0w + 16 + fr) * 32 + sw;

  auto stage = [&](int t, int buf) {
    GLD(gArow + (size_t)t * 32, &lds[buf][wid * 512]);
    int kg = t * 32 + sSwz * 8;  // kg<512 uniform per t (sSwz*8 <= 24)
    const half_t* hsrc = (kg < 512) ? h0in : hB;
    GLD(hsrc + bb * 512 + (kg & 511), &lds[buf][2048 + wid * 512]);
  };

  f32x4 acc00 = {0.f, 0.f, 0.f, 0.f};
  f32x4 acc01 = acc00, acc10 = acc00, acc11 = acc00;

  auto compute = [&](int buf) {
    const half_t* L = &lds[buf][0];
    f16x8 a0 = *(const f16x8*)&L[ia0];
    f16x8 a1 = *(const f16x8*)&L[ia1];
    f16x8 b0 = *(const f16x8*)&L[ib0];
    f16x8 b1 = *(const f16x8*)&L[ib1];
    acc00 = __builtin_amdgcn_mfma_f32_16x16x32_f16(a0, b0, acc00, 0, 0, 0);
    acc01 = __builtin_amdgcn_mfma_f32_16x16x32_f16(a0, b1, acc01, 0, 0, 0);
    acc10 = __builtin_amdgcn_mfma_f32_16x16x32_f16(a1, b0, acc10, 0, 0, 0);
    acc11 = __builtin_amdgcn_mfma_f32_16x16x32_f16(a1, b1, acc11, 0, 0, 0);
  };

  stage(0, 0);
  stage(1, 1);
  stage(2, 2);
  int t = 0;
  for (; t < KT - 3; ++t) {
    PHASE_WAIT(4);
    stage(t + 3, (t + 3) & 3);
    compute(t & 3);
  }
  PHASE_WAIT(4);
  compute(t & 3);
  ++t;
  PHASE_WAIT(2);
  compute(t & 3);
  ++t;
  PHASE_WAIT(0);
  compute(t & 3);

#pragma unroll
  for (int am = 0; am < 2; ++am) {
#pragma unroll
    for (int bn = 0; bn < 2; ++bn) {
      f32x4 a = am == 0 ? (bn == 0 ? acc00 : acc01) : (bn == 0 ? acc10 : acc11);
      int Rb = blockIdx.y * 64 + r0 + am * 16 + fc * 4;  // row base, gate = j
      int u = Rb >> 2;
      int b = blockIdx.x * 64 + c0w + bn * 16 + fr;
      float p[4];
#pragma unroll
      for (int j = 0; j < 4; ++j) {
        float s = a[j];
        s += isL1 ? bg1[j * 512 + u] : xw0[b * 2048 + j * 512 + u];
        p[j] = s;
      }
      int ci = b * 512 + u;
      float cprev = c[ci];
      float ig = sig_(p[0]);
      float fg = sig_(p[1]);
      float gg = tanhf(p[2]);
      float og = sig_(p[3]);
      float cn = fg * cprev + ig * gg;
      float hn = og * tanhf(cn);
      c[ci] = cn;
      hout[ci] = f2h(hn);
      if (isL1) ysout[ci] = f2h(hn);
    }
  }
}

// ---------------- final FC: sigmoid(fc1o @ fw2.T + fb2), [2560,13] ----------------
__global__ void fc2_sigmoid(const half_t* __restrict__ in, const float* __restrict__ w,
                            const float* __restrict__ b, float* __restrict__ out) {
  int idx = blockIdx.x * blockDim.x + threadIdx.x;
  if (idx >= 2560 * 13) return;
  int j = idx % 13, r = idx / 13;
  const half_t* ip = in + (size_t)r * 512;
  const float* wp = w + j * 512;
  float s = b[j];
  for (int k = 0; k < 512; k += 8) {
    f16x8 hv = *(const f16x8*)&ip[k];
#pragma unroll
    for (int q = 0; q < 8; ++q) s = fmaf((float)hv[q], wp[k + q], s);
  }
  out[idx] = sig_(s);
}

// ---------------- launch ----------------
extern "C" void kernel_launch(void* const* d_in, const int* in_sizes, int n_in,
                              void* d_out, int out_size, void* d_ws, size_t ws_size,
                              hipStream_t stream) {
  const float* x   = (const float*)d_in[0];
  const float* w1  = (const float*)d_in[1];  const float* b1 = (const float*)d_in[2];
  const float* w2  = (const float*)d_in[3];  const float* b2 = (const float*)d_in[4];
  const float* w3  = (const float*)d_in[5];  const float* b3 = (const float*)d_in[6];
  const float* w4  = (const float*)d_in[7];  const float* b4 = (const float*)d_in[8];
  const float* w5  = (const float*)d_in[9];  const float* b5 = (const float*)d_in[10];
  const float* wih0 = (const float*)d_in[11]; const float* whh0 = (const float*)d_in[12];
  const float* bih0 = (const float*)d_in[13]; const float* bhh0 = (const float*)d_in[14];
  const float* wih1 = (const float*)d_in[15]; const float* whh1 = (const float*)d_in[16];
  const float* bih1 = (const float*)d_in[17]; const float* bhh1 = (const float*)d_in[18];
  const float* fw1 = (const float*)d_in[19]; const float* fb1 = (const float*)d_in[20];
  const float* fw2 = (const float*)d_in[21]; const float* fb2 = (const float*)d_in[22];
  float* out = (float*)d_out;

  // ---- workspace layout (total ~65.5 MB) ----
  float* bg0 = (float*)d_ws;               // 2048
  float* bg1 = bg0 + 2048;                 // 2048
  float* xw0 = bg1 + 2048;                 // 262144
  float* c0  = xw0 + 262144;               // 65536
  float* c1  = c0 + 65536;                 // 65536
  half_t* h0a = (half_t*)(c1 + 65536);     // 65536 h each (c0..h1b zeroed together)
  half_t* h0b = h0a + 65536;
  half_t* h1a = h0b + 65536;
  half_t* h1b = h1a + 65536;
  half_t* U    = h1b + 65536;
  half_t* xpad = U;                        // 5,017,600   [A4 overlays]
  half_t* BUF1 = xpad + 5017600;           // 8,388,608   [A1 -> A3 -> feat+pbuf5]
  half_t* BUF2 = BUF1 + 8388608;           // 2,768,896   [A2 -> ys+fc1o]
  half_t* w1r  = BUF2 + 2768896;           // 26,624
  half_t* w2r  = w1r + 26624;              // 401,408
  half_t* w3r  = w2r + 401408;             // 819,200
  half_t* w4r  = w3r + 819200;             // 3,276,800
  half_t* w5r  = w4r + 3276800;            // 6,553,600
  half_t* wih0h  = w5r + 6553600;          // 1,048,576
  half_t* wcat0h = wih0h + 1048576;        // 1,048,576
  half_t* wcat1h = wcat0h + 1048576;       // 2,097,152
  half_t* fw1h   = wcat1h + 2097152;       // 262,144

  half_t* A1 = BUF1;                       // [128,32,32,64] NHWC fp16
  half_t* A2 = BUF2;                       // [128,13,13,128]
  half_t* A3 = BUF1;                       // [128,9,9,256]
  half_t* A4 = xpad;                       // [128,5,5,512]
  half_t* feat = BUF1;                     // [128,512] fp16 (A3 dead)
  float* pbuf5 = (float*)(BUF1 + 65536);   // 25 x 65536 f32 partials (A3 dead)
  half_t* ys   = BUF2;                     // [2560,512] fp16 (A2 dead)
  half_t* fc1o = BUF2 + 1310720;           // [2560,512] fp16

  dim3 blk(256);

  // ---- prep ----
  add_pair_f32<<<8, blk, 0, stream>>>(bih0, bhh0, bg0, 2048);
  add_pair_f32<<<8, blk, 0, stream>>>(bih1, bhh1, bg1, 2048);
  zero_f32<<<1024, blk, 0, stream>>>(c0, 262144);  // c0,c1 + h0a,h0b,h1a,h1b
  pad_x_kernel<<<19600, blk, 0, stream>>>(x, xpad);
  reorder_w1_kernel<<<104, blk, 0, stream>>>(w1, w1r);
  reorder_w_kernel<<<1568, blk, 0, stream>>>(w2, w2r, 401408, 3136, 7, 7, 6);
  reorder_w_kernel<<<3200, blk, 0, stream>>>(w3, w3r, 819200, 3200, 5, 5, 7);
  reorder_w_kernel<<<12800, blk, 0, stream>>>(w4, w4r, 3276800, 6400, 5, 5, 8);
  reorder_w_kernel<<<25600, blk, 0, stream>>>(w5, w5r, 6553600, 12800, 5, 5, 9);
  cast_f16<<<4096, blk, 0, stream>>>(wih0, wih0h, 1048576);
  cast_f16<<<1024, blk, 0, stream>>>(fw1, fw1h, 262144);
  build_wcat0<<<4096, blk, 0, stream>>>(whh0, wcat0h);
  build_wcat1<<<8192, blk, 0, stream>>>(wih1, whh1, wcat1h);

  // ---- conv stack (fp16 MFMA, leaky 0.2) ----
  conv_mfma<7, 2, 3, 0><<<dim3(2048, 1, 1), blk, 0, stream>>>(
      xpad, w1r, b1, A1, 70, 70, 32, 32, 64, 416, 13, 0.2f);
  conv_mfma<7, 2, 6, 0><<<dim3(338, 2, 1), blk, 0, stream>>>(
      A1, w2r, b2, A2, 32, 32, 13, 13, 128, 3136, 98, 0.2f);
  conv_mfma<5, 1, 7, 0><<<dim3(162, 4, 1), blk, 0, stream>>>(
      A2, w3r, b3, A3, 13, 13, 9, 9, 256, 3200, 100, 0.2f);
  conv_mfma<5, 1, 8, 0><<<dim3(50, 8, 1), blk, 0, stream>>>(
      A3, w4r, b4, A4, 9, 9, 5, 5, 512, 6400, 200, 0.2f);
  // conv5: K-split x25 into f32 partials, then finalize -> feat fp16
  conv_mfma<5, 1, 9, 2><<<dim3(2, 8, 25), blk, 0, stream>>>(
      A4, w5r, b5, pbuf5, 5, 5, 1, 1, 512, 12800, 16, 0.2f);
  finalize5<<<256, blk, 0, stream>>>(pbuf5, b5, feat);

  // xw0 = feat @ wih0.T + bg0   [128][2048], f32, identity act (slope=1)
  conv_mfma<1, 1, 9, 1><<<dim3(2, 32, 1), blk, 0, stream>>>(
      feat, wih0h, bg0, xw0, 1, 1, 1, 1, 2048, 512, 16, 1.0f);

  // ---- 2-layer LSTM, 20 steps, fused l0(t+1)||l1(t): 21 launches ----
  half_t* h0buf[2] = {h0a, h0b};
  half_t* h1buf[2] = {h1a, h1b};
  // launch 1: l0 step1 (reads H0_0=h0a zeros -> writes h0b)
  lstm_fused<<<dim3(2, 32, 1), blk, 0, stream>>>(
      h0a, h0b, h1a, h1a, wcat0h, wcat1h, xw0, bg1, c0, c1, ys, 1);
  // launches t=2..20: l0 step t || l1 step t-1
  for (int t = 2; t <= 20; ++t) {
    lstm_fused<<<dim3(2, 32, 2), blk, 0, stream>>>(
        h0buf[(t - 1) & 1], h0buf[t & 1], h1buf[t & 1], h1buf[(t - 1) & 1],
        wcat0h, wcat1h, xw0, bg1, c0, c1, ys + (size_t)(t - 2) * 65536, 3);
  }
  // launch 21: l1 step 20 (reads H0_20=h0buf[0], H1_19=h1buf[1])
  lstm_fused<<<dim3(2, 32, 1), blk, 0, stream>>>(
      h0buf[0], h0buf[1], h1buf[1], h1buf[0],
      wcat0h, wcat1h, xw0, bg1, c0, c1, ys + (size_t)19 * 65536, 2);

  // ---- FC head ----
  conv_mfma<1, 1, 9, 0><<<dim3(40, 8, 1), blk, 0, stream>>>(
      ys, fw1h, fb1, fc1o, 1, 1, 1, 1, 512, 512, 16, 0.01f);
  fc2_sigmoid<<<130, blk, 0, stream>>>(fc1o, fw2, fb2, out);
}